// Round 2
// 2842.933 us; speedup vs baseline: 1.7004x; 1.7004x over previous
//
#include <hip/hip_runtime.h>
#include <stdint.h>

#define NROWS 16384
#define NZ    8192
#define NCLUST 16
#define DSUB  512

typedef __attribute__((ext_vector_type(8))) short short8;
typedef __attribute__((ext_vector_type(4))) float floatx4;

__device__ __forceinline__ unsigned short f2bf(float f) {
  unsigned int u = __float_as_uint(f);
  u += 0x7fffu + ((u >> 16) & 1u);   // round-to-nearest-even
  return (unsigned short)(u >> 16);
}

__device__ __forceinline__ void async_copy16(void* lds, const void* g) {
  __builtin_amdgcn_global_load_lds(
      (const __attribute__((address_space(1))) unsigned int*)g,
      (__attribute__((address_space(3))) unsigned int*)lds,
      16, 0, 0);
}

// ---- zero the s-partials (ws is poisoned 0xAA every call) ----
__global__ void zero_s(float* __restrict__ s) {
  s[blockIdx.x * 256 + threadIdx.x] = 0.0f;
}

// ---- z: fp32 -> out copy + bf16 convert into ws ----
__global__ void convert_copy_z(const float4* __restrict__ z,
                               float4* __restrict__ zout,
                               ushort4* __restrict__ zb) {
  int i = blockIdx.x * 256 + threadIdx.x;
  float4 v = z[i];
  zout[i] = v;
  ushort4 b;
  b.x = f2bf(v.x); b.y = f2bf(v.y); b.z = f2bf(v.z); b.w = f2bf(v.w);
  zb[i] = b;
}

// ---- D [K][N] fp32 -> Dt [N][K] bf16 (so GEMM B reads row-major over K) ----
__global__ void transpose_convert_D(const float* __restrict__ D,
                                    unsigned short* __restrict__ Dt) {
  __shared__ float tile[32][33];
  const int tx = threadIdx.x, ty = threadIdx.y;
  const int nb = blockIdx.x * 32, kb = blockIdx.y * 32;
#pragma unroll
  for (int r = 0; r < 4; ++r)
    tile[ty + r * 8][tx] = D[(size_t)(kb + ty + r * 8) * NZ + nb + tx];
  __syncthreads();
#pragma unroll
  for (int r = 0; r < 4; ++r)
    Dt[(size_t)(nb + ty + r * 8) * NZ + kb + tx] = f2bf(tile[tx][ty + r * 8]);
}

// ============================================================================
// 256x256x(BK=64) bf16 GEMM, 8 waves (2Mx4N), 8-phase schedule, counted vmcnt,
// XOR-swizzled LDS (write-side via pre-swizzled global src, read-side via XOR),
// XCD-aware block swizzle, setprio around MFMA clusters.
// LDS 128 KiB: A[2][256][64] | B[2][256][64] bf16.
//
// Phase-safety rule: STG into region R at phase q requires every read of R
// to be in a phase <= q-1 (reads complete at that phase's lgkmcnt(0), before
// its end barrier; the STG is issued after that barrier). A-halves are read
// in BOTH p1 and p3 (wm=0 reads rows 0-127 across p1/p3; wm=1 rows 128-255),
// so both A stages sit in the register-only phases p4/p8.
// ============================================================================

#define BAR        __builtin_amdgcn_s_barrier()
#define DSB        __builtin_amdgcn_sched_barrier(0)
#define WAIT_LGKM0 asm volatile("s_waitcnt lgkmcnt(0)" ::: "memory")
#define WAIT_VM6   asm volatile("s_waitcnt vmcnt(6)" ::: "memory")
#define WAIT_VM0   asm volatile("s_waitcnt vmcnt(0)" ::: "memory")

// stage one 128x64 half-tile: 2 x global_load_lds per thread
#define STG(gbase, hro, tk, d)                                              \
  do {                                                                      \
    const short* _g = (gbase) + (size_t)(hro) * NZ + (size_t)(tk) * 64;     \
    async_copy16((d), _g);                                                  \
    async_copy16((d) + 4096, _g + (size_t)64 * NZ);                         \
  } while (0)

#define LOAD_A(ih, buf)                                                     \
  do {                                                                      \
    _Pragma("unroll") for (int i = 0; i < 4; ++i) {                         \
      const short* _p = &lds[(buf) * 16384 + aRow + ((ih) * 4 + i) * 1024]; \
      af[i][0] = *(const short8*)(_p + cx0);                                \
      af[i][1] = *(const short8*)(_p + cx1);                                \
    }                                                                       \
  } while (0)

#define LOAD_B(jh, buf, arr)                                                \
  do {                                                                      \
    _Pragma("unroll") for (int j = 0; j < 2; ++j) {                         \
      const short* _p =                                                     \
          &lds[32768 + (buf) * 16384 + bRow + ((jh) * 2 + j) * 1024];       \
      arr[j][0] = *(const short8*)(_p + cx0);                               \
      arr[j][1] = *(const short8*)(_p + cx1);                               \
    }                                                                       \
  } while (0)

#define MFMA_Q(i0, j0, arr)                                                 \
  do {                                                                      \
    __builtin_amdgcn_s_setprio(1);                                          \
    _Pragma("unroll") for (int i = 0; i < 4; ++i)                           \
    _Pragma("unroll") for (int j = 0; j < 2; ++j) {                         \
      acc[(i0) + i][(j0) + j] = __builtin_amdgcn_mfma_f32_16x16x32_bf16(    \
          af[i][0], arr[j][0], acc[(i0) + i][(j0) + j], 0, 0, 0);           \
      acc[(i0) + i][(j0) + j] = __builtin_amdgcn_mfma_f32_16x16x32_bf16(    \
          af[i][1], arr[j][1], acc[(i0) + i][(j0) + j], 0, 0, 0);           \
    }                                                                       \
    __builtin_amdgcn_s_setprio(0);                                          \
  } while (0)

__global__ __launch_bounds__(512, 2) void gemm256(
    const short* __restrict__ zb, const short* __restrict__ dtb,
    float* __restrict__ s_un) {
  __shared__ __align__(16) short lds[65536];   // 128 KiB

  const int t = threadIdx.x;
  const int w = t >> 6;        // wave 0..7
  const int l = t & 63;
  const int wm = w >> 2;       // 0..1  -> rows wm*128
  const int wn = w & 3;        // 0..3  -> cols wn*64
  const int quad = l >> 4;
  const int r16 = l & 15;

  // XCD-aware swizzle: 2048 blocks (bijective, 2048 % 8 == 0)
  const int bid = blockIdx.x;
  const int swz = (bid & 7) * 256 + (bid >> 3);
  const int m0 = (swz >> 5) * 256;   // 64 M-tiles
  const int n0 = (swz & 31) * 256;   // 32 N-tiles

  // staging source (per-lane, XOR pre-swizzled so linear LDS dest = swizzled)
  const int rsub = l >> 3;               // 0..7
  const int cg = (l & 7) ^ rsub;         // global 16B-chunk index
  const size_t g_off = (size_t)(w * 8 + rsub) * NZ + cg * 8;
  const short* gA = zb + (size_t)m0 * NZ + g_off;
  const short* gB = dtb + (size_t)n0 * NZ + g_off;
  short* const ldA = &lds[w * 512];              // wave-uniform dests
  short* const ldB = &lds[32768 + w * 512];

  // fragment read offsets (LDS chunk c of row r holds global chunk c^(r&7))
  const int aRow = (wm * 128 + r16) * 64;
  const int bRow = (wn * 64 + r16) * 64;
  const int cx0 = ((quad) ^ (r16 & 7)) * 8;        // global chunk quad (k 0..31)
  const int cx1 = ((4 + quad) ^ (r16 & 7)) * 8;    // global chunk 4+quad (k 32..63)

  floatx4 acc[8][4];
#pragma unroll
  for (int i = 0; i < 8; ++i)
#pragma unroll
    for (int j = 0; j < 4; ++j)
      acc[i][j] = {0.0f, 0.0f, 0.0f, 0.0f};
  short8 af[4][2], bf0[2][2], bf1[2][2];

  // ---- prologue: tile0 full, tile1 {Bn1, Am0, Am1} (Bn0 comes in p1) ----
  STG(gB, 0,   0, ldB);                   // T0.Bn0
  STG(gB, 128, 0, ldB + 8192);            // T0.Bn1
  STG(gA, 0,   0, ldA);                   // T0.Am0
  STG(gA, 128, 0, ldA + 8192);            // T0.Am1
  STG(gB, 128, 1, ldB + 16384 + 8192);    // T1.Bn1
  STG(gA, 0,   1, ldA + 16384);           // T1.Am0
  STG(gA, 128, 1, ldA + 16384 + 8192);    // T1.Am1
  WAIT_VM6;   // oldest 8 = all of tile0; 6 outstanding = tile1 partial
  BAR;

  // ---- main loop: iteration computes tiles 2it (buf0), 2it+1 (buf1) ----
#pragma unroll 1
  for (int it = 0; it < 63; ++it) {
    const int t1 = 2 * it + 1, t2 = 2 * it + 2, t3 = 2 * it + 3;
    // p1: q(m0,n0) of T0            | stage T1.Bn0 -> buf1 (last read prev p6)
    LOAD_A(0, 0); LOAD_B(0, 0, bf0);
    STG(gB, 0, t1, ldB + 16384);
    BAR; WAIT_LGKM0; DSB; MFMA_Q(0, 0, bf0); BAR;
    // p2: q(m0,n1)                  | no stage
    LOAD_B(1, 0, bf1);
    BAR; WAIT_LGKM0; DSB; MFMA_Q(0, 2, bf1); BAR;
    // p3: q(m1,n1)                  | stage T2.Bn1 -> buf0 (reads p1,p2)
    LOAD_A(1, 0);
    STG(gB, 128, t2, ldB + 8192);
    BAR; WAIT_LGKM0; DSB; MFMA_Q(4, 2, bf1); BAR;
    // p4: q(m1,n0) (regs only)      | stage T2.Am0+Am1 -> buf0 (reads p1,p3)
    STG(gA, 0,   t2, ldA);
    STG(gA, 128, t2, ldA + 8192);
    WAIT_VM6;   // oldest 8 = all of T1 (prev p7, prev p8, cur p1)
    BAR; WAIT_LGKM0; DSB; MFMA_Q(4, 0, bf0); BAR;
    // p5: q(m0,n0) of T1            | stage T2.Bn0 -> buf0 (reads p1,p2)
    LOAD_A(0, 1); LOAD_B(0, 1, bf0);
    STG(gB, 0, t2, ldB);
    BAR; WAIT_LGKM0; DSB; MFMA_Q(0, 0, bf0); BAR;
    // p6: q(m0,n1)                  | no stage
    LOAD_B(1, 1, bf1);
    BAR; WAIT_LGKM0; DSB; MFMA_Q(0, 2, bf1); BAR;
    // p7: q(m1,n1)                  | stage T3.Bn1 -> buf1 (reads p5,p6)
    LOAD_A(1, 1);
    STG(gB, 128, t3, ldB + 16384 + 8192);
    BAR; WAIT_LGKM0; DSB; MFMA_Q(4, 2, bf1); BAR;
    // p8: q(m1,n0) (regs only)      | stage T3.Am0+Am1 -> buf1 (reads p5,p7)
    STG(gA, 0,   t3, ldA + 16384);
    STG(gA, 128, t3, ldA + 16384 + 8192);
    WAIT_VM6;   // oldest 8 = all of T2 (cur p3, p4, p5)
    BAR; WAIT_LGKM0; DSB; MFMA_Q(4, 0, bf0); BAR;
  }

  // ---- tail: tiles 126 (buf0), 127 (buf1) ----
  LOAD_A(0, 0); LOAD_B(0, 0, bf0);
  STG(gB, 0, 127, ldB + 16384);          // T127.Bn0 (last missing half)
  BAR; WAIT_LGKM0; DSB; MFMA_Q(0, 0, bf0); BAR;
  LOAD_B(1, 0, bf1);
  BAR; WAIT_LGKM0; DSB; MFMA_Q(0, 2, bf1); BAR;
  LOAD_A(1, 0);
  BAR; WAIT_LGKM0; DSB; MFMA_Q(4, 2, bf1); BAR;
  WAIT_VM0;                              // drain: tile 127 fully landed
  BAR; WAIT_LGKM0; DSB; MFMA_Q(4, 0, bf0); BAR;
  LOAD_A(0, 1); LOAD_B(0, 1, bf0);
  BAR; WAIT_LGKM0; DSB; MFMA_Q(0, 0, bf0); BAR;
  LOAD_B(1, 1, bf1);
  BAR; WAIT_LGKM0; DSB; MFMA_Q(0, 2, bf1); BAR;
  LOAD_A(1, 1);
  BAR; WAIT_LGKM0; DSB; MFMA_Q(4, 2, bf1); BAR;
  WAIT_LGKM0; DSB; MFMA_Q(4, 0, bf0);

  // ---- epilogue: sum of squares over this block's 256 cols (one cluster) ----
  const int cluster = n0 >> 9;
#pragma unroll
  for (int i = 0; i < 8; ++i) {
    floatx4 v = acc[i][0] * acc[i][0];
#pragma unroll
    for (int j = 1; j < 4; ++j)
      v += acc[i][j] * acc[i][j];
#pragma unroll
    for (int m = 1; m < 16; m <<= 1) {
#pragma unroll
      for (int c = 0; c < 4; ++c)
        v[c] += __shfl_xor(v[c], m);
    }
    if (r16 == 0) {
      const int rb = m0 + wm * 128 + i * 16 + quad * 4;
      atomicAdd(&s_un[(rb + 0) * NCLUST + cluster], v[0]);
      atomicAdd(&s_un[(rb + 1) * NCLUST + cluster], v[1]);
      atomicAdd(&s_un[(rb + 2) * NCLUST + cluster], v[2]);
      atomicAdd(&s_un[(rb + 3) * NCLUST + cluster], v[3]);
    }
  }
}

// ---- (S + eta*d)/((eta+1)*d), row-normalize ----
__global__ void finalize_s(const float* __restrict__ s_un, float* __restrict__ out) {
  int r = blockIdx.x * 256 + threadIdx.x;
  float v[NCLUST];
  float tot = 0.0f;
#pragma unroll
  for (int i = 0; i < NCLUST; ++i) {
    v[i] = (s_un[r * NCLUST + i] + 2560.0f) * (1.0f / 3072.0f);
    tot += v[i];
  }
  float inv = 1.0f / tot;
#pragma unroll
  for (int i = 0; i < NCLUST; ++i)
    out[r * NCLUST + i] = v[i] * inv;
}

extern "C" void kernel_launch(void* const* d_in, const int* in_sizes, int n_in,
                              void* d_out, int out_size, void* d_ws, size_t ws_size,
                              hipStream_t stream) {
  const float* z = (const float*)d_in[0];
  const float* D = (const float*)d_in[1];
  float* out_s = (float*)d_out;
  float* out_z = out_s + (size_t)NROWS * NCLUST;

  // ws layout: z_bf16 (256 MiB) | Dt_bf16 (128 MiB) | s_unnorm (1 MiB)
  char* ws = (char*)d_ws;
  short* zb = (short*)ws;
  unsigned short* dtb = (unsigned short*)(ws + (size_t)NROWS * NZ * 2);
  float* s_un = (float*)(ws + (size_t)NROWS * NZ * 2 + (size_t)NZ * NZ * 2);

  zero_s<<<(NROWS * NCLUST) / 256, 256, 0, stream>>>(s_un);

  convert_copy_z<<<(int)(((size_t)NROWS * NZ / 4) / 256), 256, 0, stream>>>(
      (const float4*)z, (float4*)out_z, (ushort4*)zb);

  dim3 tg(NZ / 32, NZ / 32);
  transpose_convert_D<<<tg, dim3(32, 8), 0, stream>>>(D, dtb);

  gemm256<<<2048, 512, 0, stream>>>(zb, (const short*)dtb, s_un);

  finalize_s<<<NROWS / 256, 256, 0, stream>>>(s_un, out_s);
}